// Round 6
// baseline (273.341 us; speedup 1.0000x reference)
//
#include <hip/hip_runtime.h>

#define BB 4
#define CIN 256
#define HW 35200            // 200*176
#define AA 6
#define NANCH (AA * HW)     // 211200
#define TOPK 100
#define NBIN 4096           // mapped score bins
#define BINBASE 28416       // 0x37800000 >> 15  (s = 2^-16 .. 1.0 range)
#define CAP 4096            // candidates per batch
#define SMAX 4096           // bitonic sort max size
#define TILES 138           // ceil(HW/256): each k1 block covers 256 hw
#define ZEROWORDS (BB * NBIN + 16)   // hist + cand_count

// monotone (clamped) bin map for score bits, s in [0,1]
__device__ __forceinline__ unsigned sbin(unsigned bits) {
  int v = (int)(bits >> 15) - BINBASE;
  v = v < 0 ? 0 : v;
  v = v > (NBIN - 1) ? (NBIN - 1) : v;
  return (unsigned)v;
}

__device__ __forceinline__ float sc4(float4 l) {
  float m = fmaxf(fmaxf(l.x, l.y), fmaxf(l.z, l.w));
  float e0 = expf(l.x - m), e1 = expf(l.y - m);
  float e2 = expf(l.z - m), e3 = expf(l.w - m);
  return fmaxf(fmaxf(e1, e2), e3) / (e0 + e1 + e2 + e3);
}

#define FMA4(A, W, S)                                      \
  A.x = fmaf(S, W.x, A.x); A.y = fmaf(S, W.y, A.y);        \
  A.z = fmaf(S, W.z, A.z); A.w = fmaf(S, W.w, A.w);

// ---------------- K0: zero counters ----------------
__global__ __launch_bounds__(256) void k0_init(unsigned int* __restrict__ zr) {
  int t = blockIdx.x * 256 + threadIdx.x;
  int stride = gridDim.x * 256;
  for (int i = t; i < ZEROWORDS; i += stride) zr[i] = 0u;
}

// ---------------- K1: cls head -> scores + LDS histogram ----------------
// LDS-pipe fix: each ds_read_b128 of weights now feeds 2 hw positions
// (float2 per thread) and channels are split 2-way across wave-pairs, so
// per-block weight ds_reads halve vs the 90us baseline.  VALU (96 cyc/ch)
// now covers LDS (72 cyc/ch).  x loads 8-deep ILP, coalesced 8B/lane.
__global__ __launch_bounds__(256, 2) void k1_scores(
    const float* __restrict__ x, const float* __restrict__ cls_w,
    const float* __restrict__ cls_b, unsigned int* __restrict__ hist,
    float* __restrict__ maxsc) {
  int bid = blockIdx.x;
  int b = bid / TILES, tile = bid % TILES;
  int tid = threadIdx.x;

  __shared__ __align__(16) float swf[CIN * 24];   // 24 KB weights [c][o]
  __shared__ unsigned lh[NBIN];                   // 16 KB block-local histogram
  __shared__ float4 sred[128][13];                // 26 KB split-1 partials (pad: 8-way max)

  for (int i = tid; i < CIN * 24; i += 256)
    swf[(i % CIN) * 24 + (i / CIN)] = cls_w[i];   // coalesced global read
  for (int i = tid; i < NBIN; i += 256) lh[i] = 0;
  __syncthreads();

  int l = tid & 127;            // hw-pair lane [0,128)
  int s = tid >> 7;             // channel split {0,1} (wave-pair uniform)
  int hw0 = tile * 256 + 2 * l;
  bool act = hw0 < HW;          // HW even -> hw0+1 also valid when act
  const float* xb = x + (size_t)b * CIN * HW + (act ? hw0 : 0);
  int c0 = s * 128;

  float4 acc[2][6];             // [hw][anchor], 48 VGPRs
#pragma unroll
  for (int h = 0; h < 2; ++h)
#pragma unroll
    for (int j = 0; j < 6; ++j) acc[h][j] = make_float4(0.f, 0.f, 0.f, 0.f);

#pragma unroll 1
  for (int cc = 0; cc < 128; cc += 8) {
    float2 xv[8];
#pragma unroll
    for (int u = 0; u < 8; ++u)        // 8 independent HBM loads in flight
      xv[u] = *(const float2*)(xb + (size_t)(c0 + cc + u) * HW);
#pragma unroll
    for (int u = 0; u < 8; ++u) {
      const float4* wr = (const float4*)&swf[(c0 + cc + u) * 24];
      float4 w0 = wr[0], w1 = wr[1], w2 = wr[2];
      float4 w3 = wr[3], w4 = wr[4], w5 = wr[5];
      float x0 = xv[u].x, x1 = xv[u].y;
      FMA4(acc[0][0], w0, x0) FMA4(acc[1][0], w0, x1)
      FMA4(acc[0][1], w1, x0) FMA4(acc[1][1], w1, x1)
      FMA4(acc[0][2], w2, x0) FMA4(acc[1][2], w2, x1)
      FMA4(acc[0][3], w3, x0) FMA4(acc[1][3], w3, x1)
      FMA4(acc[0][4], w4, x0) FMA4(acc[1][4], w4, x1)
      FMA4(acc[0][5], w5, x0) FMA4(acc[1][5], w5, x1)
    }
  }

  if (s == 1) {                       // split 1 parks partials in LDS
#pragma unroll
    for (int j = 0; j < 6; ++j) {
      sred[l][j] = acc[0][j];
      sred[l][6 + j] = acc[1][j];
    }
  }
  __syncthreads();
  if (s == 0 && act) {                // split 0 reduces + softmax + hist
    const float4* bias4 = (const float4*)cls_b;
    float* mp = maxsc + (size_t)b * NANCH + (size_t)hw0 * 6u;
#pragma unroll
    for (int h = 0; h < 2; ++h) {
#pragma unroll
      for (int j = 0; j < 6; ++j) {
        float4 v = acc[h][j];
        float4 o = sred[l][h * 6 + j];
        float4 bb = bias4[j];
        v.x += o.x + bb.x; v.y += o.y + bb.y;
        v.z += o.z + bb.z; v.w += o.w + bb.w;
        float sc = sc4(v);
        mp[h * 6 + j] = sc;           // 12 contiguous floats/thread -> coalesced
        atomicAdd(&lh[sbin(__float_as_uint(sc))], 1u);
      }
    }
  }
  __syncthreads();
  unsigned* gh = hist + (size_t)b * NBIN;
  for (int i = tid; i < NBIN; i += 256) {
    unsigned c = lh[i];
    if (c) atomicAdd(&gh[i], c);   // device-coherent; k2 reads after dispatch boundary
  }
}

// ---------------- K2: threshold bin per batch ----------------
__global__ __launch_bounds__(256) void k2_thresh(
    const unsigned int* __restrict__ hist, unsigned int* __restrict__ thresh) {
  int b = blockIdx.x, tid = threadIdx.x;
  const unsigned* h = hist + (size_t)b * NBIN;
  unsigned r[16];
  unsigned s = 0;
#pragma unroll
  for (int i = 0; i < 16; ++i) { r[i] = h[tid * 16 + i]; s += r[i]; }
  __shared__ unsigned seg[256];
  seg[tid] = s;
  __syncthreads();
  for (int d = 1; d < 256; d <<= 1) {   // inclusive suffix scan
    unsigned add = (tid + d < 256) ? seg[tid + d] : 0u;
    __syncthreads();
    seg[tid] += add;
    __syncthreads();
  }
  unsigned above = (tid < 255) ? seg[tid + 1] : 0u;
  if (above < TOPK && above + s >= TOPK) {   // exactly one thread
    unsigned c = above, T = 0;
    for (int i = 15; i >= 0; --i) {
      c += r[i];
      if (c >= TOPK) { T = tid * 16u + (unsigned)i; break; }
    }
    thresh[b] = T;
  }
}

// ---------------- K3: compact candidates (wave-aggregated atomics) ----------------
__global__ __launch_bounds__(256) void k3_compact(
    const float* __restrict__ maxsc, const unsigned int* __restrict__ thresh,
    unsigned int* __restrict__ cand_count, unsigned long long* __restrict__ cand) {
  unsigned p = blockIdx.x * 256u + threadIdx.x;   // [0, B*NANCH)
  unsigned b = p / NANCH, n = p % NANCH;          // b block-uniform (NANCH%256==0)
  unsigned bits = __float_as_uint(maxsc[p]);
  bool pred = sbin(bits) >= thresh[b];
  unsigned long long mask = __ballot(pred);
  if (mask) {
    int lane = threadIdx.x & 63;
    int leader = (int)__ffsll(mask) - 1;
    unsigned base = 0;
    if (lane == leader)
      base = atomicAdd(&cand_count[b], (unsigned)__popcll(mask));
    base = __shfl(base, leader, 64);
    if (pred) {
      unsigned pos = base + (unsigned)__popcll(mask & ((1ull << lane) - 1ull));
      if (pos < CAP)
        cand[(size_t)b * CAP + pos] =
            ((unsigned long long)bits << 32) | (unsigned)(~n);
    }
  }
}

// ---------------- K4: bitonic sort candidates, emit topk ----------------
__global__ __launch_bounds__(256) void k4_sort(
    const unsigned long long* __restrict__ cand,
    const unsigned int* __restrict__ cand_count, unsigned int* __restrict__ topk) {
  int b = blockIdx.x, tid = threadIdx.x;
  __shared__ unsigned long long sh[SMAX];
  unsigned cnt = cand_count[b];
  if (cnt > CAP) cnt = CAP;
  unsigned S = 128;
  while (S < cnt) S <<= 1;
  for (unsigned t = tid; t < S; t += 256)
    sh[t] = (t < cnt) ? cand[(size_t)b * CAP + t] : 0ULL;
  __syncthreads();
  for (unsigned kk = 2; kk <= S; kk <<= 1) {
    for (unsigned jj = kk >> 1; jj > 0; jj >>= 1) {
      for (unsigned t = tid; t < S; t += 256) {
        unsigned ixj = t ^ jj;
        if (ixj > t) {
          unsigned long long a = sh[t], c = sh[ixj];
          bool sw = ((t & kk) == 0) ? (a < c) : (a > c);  // descending
          if (sw) { sh[t] = c; sh[ixj] = a; }
        }
      }
      __syncthreads();
    }
  }
  if (tid < TOPK)
    topk[b * TOPK + tid] = ~(unsigned)(sh[tid] & 0xFFFFFFFFULL);
}

// ---------------- K5: final heads + decode for selected anchors ----------------
__global__ __launch_bounds__(256) void k5_out(
    const float* __restrict__ x, const float* __restrict__ cls_w,
    const float* __restrict__ cls_b, const float* __restrict__ reg_w,
    const float* __restrict__ reg_b, const float* __restrict__ anchors,
    const unsigned int* __restrict__ topk, float* __restrict__ out) {
  int bk = blockIdx.x;            // [0, B*TOPK)
  int b = bk / TOPK, k = bk % TOPK;
  unsigned n = topk[b * TOPK + k];
  int a = (int)(n % AA);
  unsigned hw = n / AA;
  int tid = threadIdx.x;          // 256 == CIN

  float xv = x[(size_t)b * CIN * HW + (size_t)tid * HW + hw];
  float part[11];
#pragma unroll
  for (int j = 0; j < 4; ++j) part[j] = xv * cls_w[(a * 4 + j) * CIN + tid];
#pragma unroll
  for (int j = 0; j < 7; ++j) part[4 + j] = xv * reg_w[(a * 7 + j) * CIN + tid];

#pragma unroll
  for (int j = 0; j < 11; ++j) {
    float v = part[j];
    for (int off = 32; off > 0; off >>= 1) v += __shfl_down(v, off, 64);
    part[j] = v;
  }
  __shared__ float red[4][11];
  int wave = tid >> 6, lane = tid & 63;
  if (lane == 0) {
#pragma unroll
    for (int j = 0; j < 11; ++j) red[wave][j] = part[j];
  }
  __syncthreads();
  if (tid == 0) {
    float tot[11];
#pragma unroll
    for (int j = 0; j < 11; ++j)
      tot[j] = red[0][j] + red[1][j] + red[2][j] + red[3][j];
    float l0 = tot[0] + cls_b[a * 4 + 0];
    float l1 = tot[1] + cls_b[a * 4 + 1];
    float l2 = tot[2] + cls_b[a * 4 + 2];
    float l3 = tot[3] + cls_b[a * 4 + 3];
    float m = fmaxf(fmaxf(l0, l1), fmaxf(l2, l3));
    float e0 = expf(l0 - m), e1 = expf(l1 - m);
    float e2 = expf(l2 - m), e3 = expf(l3 - m);
    float inv = 1.0f / (e0 + e1 + e2 + e3);
    float* os = out + ((size_t)b * TOPK + k) * 4;
    os[0] = e0 * inv; os[1] = e1 * inv; os[2] = e2 * inv; os[3] = e3 * inv;
    const float* an = anchors + (size_t)n * 7;
    float xa = an[0], ya = an[1], za = an[2];
    float dxa = an[3], dya = an[4], dza = an[5], ra = an[6];
    float xt = tot[4] + reg_b[a * 7 + 0];
    float yt = tot[5] + reg_b[a * 7 + 1];
    float zt = tot[6] + reg_b[a * 7 + 2];
    float dxt = tot[7] + reg_b[a * 7 + 3];
    float dyt = tot[8] + reg_b[a * 7 + 4];
    float dzt = tot[9] + reg_b[a * 7 + 5];
    float rt = tot[10] + reg_b[a * 7 + 6];
    float diag = sqrtf(dxa * dxa + dya * dya);
    float* ob = out + (size_t)BB * TOPK * 4 + ((size_t)b * TOPK + k) * 7;
    ob[0] = xt * diag + xa;
    ob[1] = yt * diag + ya;
    ob[2] = zt * dza + za;
    ob[3] = expf(dxt) * dxa;
    ob[4] = expf(dyt) * dya;
    ob[5] = expf(dzt) * dza;
    ob[6] = rt + ra;
  }
}

extern "C" void kernel_launch(void* const* d_in, const int* in_sizes, int n_in,
                              void* d_out, int out_size, void* d_ws, size_t ws_size,
                              hipStream_t stream) {
  const float* x       = (const float*)d_in[0];
  const float* cls_w   = (const float*)d_in[1];
  const float* cls_b   = (const float*)d_in[2];
  const float* reg_w   = (const float*)d_in[3];
  const float* reg_b   = (const float*)d_in[4];
  const float* anchors = (const float*)d_in[5];
  float* out = (float*)d_out;

  // workspace layout (~3.6 MB total; ws >= 4.7 MB available)
  char* ws = (char*)d_ws;
  unsigned int* hist       = (unsigned int*)(ws);                 // 64 KB
  unsigned int* cand_count = (unsigned int*)(ws + 65536);         // 64 B (zeroed with hist)
  unsigned int* thresh     = (unsigned int*)(ws + 65600);         // 64 B
  unsigned int* topk       = (unsigned int*)(ws + 65664);         // 2 KB
  unsigned long long* cand = (unsigned long long*)(ws + 67712);   // 128 KB
  float* maxsc             = (float*)(ws + 198784);               // 3.4 MB

  // kernel boundaries provide cross-block coherence for free (no fences):
  k0_init<<<80, 256, 0, stream>>>(hist);   // hist..cand_count zero region
  k1_scores<<<BB * TILES, 256, 0, stream>>>(x, cls_w, cls_b, hist, maxsc);
  k2_thresh<<<BB, 256, 0, stream>>>(hist, thresh);
  k3_compact<<<(BB * NANCH) / 256, 256, 0, stream>>>(maxsc, thresh, cand_count, cand);
  k4_sort<<<BB, 256, 0, stream>>>(cand, cand_count, topk);
  k5_out<<<BB * TOPK, 256, 0, stream>>>(x, cls_w, cls_b, reg_w, reg_b, anchors,
                                        topk, out);
}

// Round 7
// 245.526 us; speedup vs baseline: 1.1133x; 1.1133x over previous
//
#include <hip/hip_runtime.h>

#define BB 4
#define CIN 256
#define HW 35200            // 200*176
#define AA 6
#define NANCH (AA * HW)     // 211200
#define TOPK 100
#define NBIN 4096           // mapped score bins
#define BINBASE 28416       // 0x37800000 >> 15  (s = 2^-16 .. 1.0 range)
#define CAP 4096            // candidates per batch
#define SMAX 4096           // bitonic sort max size
#define TILES 138           // ceil(HW/256)
#define ZEROWORDS (BB * NBIN + 16)   // hist + cand_count

// monotone (clamped) bin map for score bits, s in [0,1]
__device__ __forceinline__ unsigned sbin(unsigned bits) {
  int v = (int)(bits >> 15) - BINBASE;
  v = v < 0 ? 0 : v;
  v = v > (NBIN - 1) ? (NBIN - 1) : v;
  return (unsigned)v;
}

__device__ __forceinline__ float sc4(float4 l) {
  float m = fmaxf(fmaxf(l.x, l.y), fmaxf(l.z, l.w));
  float e0 = expf(l.x - m), e1 = expf(l.y - m);
  float e2 = expf(l.z - m), e3 = expf(l.w - m);
  return fmaxf(fmaxf(e1, e2), e3) / (e0 + e1 + e2 + e3);
}

#define FMA4(A, W, S)                                      \
  A.x = fmaf(S, W.x, A.x); A.y = fmaf(S, W.y, A.y);        \
  A.z = fmaf(S, W.z, A.z); A.w = fmaf(S, W.w, A.w);

// ---------------- K0: zero counters + transpose cls weights to [c][o] ----------------
__global__ __launch_bounds__(256) void k0_init(
    const float* __restrict__ cls_w, float* __restrict__ wt,
    unsigned int* __restrict__ zr) {
  int t = blockIdx.x * 256 + threadIdx.x;
  int stride = gridDim.x * 256;
  for (int i = t; i < ZEROWORDS; i += stride) zr[i] = 0u;
  for (int i = t; i < 24 * CIN; i += stride)
    wt[(i % CIN) * 24 + (i / CIN)] = cls_w[i];   // coalesced read over c
}

// ---------------- K1: cls head -> scores + LDS histogram ----------------
// Round-4 verified best variant: wave-uniform scalar (s_load) weights from
// the transposed wt, 16-deep batched x-loads for ILP.  UNCHANGED.
__global__ __launch_bounds__(256, 4) void k1_scores(
    const float* __restrict__ x, const float* __restrict__ wt,
    const float* __restrict__ cls_b, unsigned int* __restrict__ hist,
    float* __restrict__ maxsc) {
  int bid = blockIdx.x;
  int b = bid / TILES, tile = bid % TILES;
  int tid = threadIdx.x;

  __shared__ unsigned lh[NBIN];        // 16 KB block-local histogram
  for (int i = tid; i < NBIN; i += 256) lh[i] = 0;
  __syncthreads();

  int hwg = tile * 256 + tid;
  bool act = hwg < HW;
  int hwc = act ? hwg : (HW - 1);
  const float* xb = x + (size_t)b * CIN * HW + hwc;

  float4 a0 = make_float4(cls_b[0], cls_b[1], cls_b[2], cls_b[3]);
  float4 a1 = make_float4(cls_b[4], cls_b[5], cls_b[6], cls_b[7]);
  float4 a2 = make_float4(cls_b[8], cls_b[9], cls_b[10], cls_b[11]);
  float4 a3 = make_float4(cls_b[12], cls_b[13], cls_b[14], cls_b[15]);
  float4 a4 = make_float4(cls_b[16], cls_b[17], cls_b[18], cls_b[19]);
  float4 a5 = make_float4(cls_b[20], cls_b[21], cls_b[22], cls_b[23]);

#pragma unroll 1
  for (int cc = 0; cc < CIN; cc += 16) {
    float xv[16];
#pragma unroll
    for (int u = 0; u < 16; ++u)       // 16 independent loads issued back-to-back
      xv[u] = xb[(size_t)(cc + u) * HW];
#pragma unroll
    for (int u = 0; u < 16; ++u) {
      const float4* wr = (const float4*)(wt + (cc + u) * 24);  // uniform -> s_load
      float4 w0 = wr[0], w1 = wr[1], w2 = wr[2];
      float4 w3 = wr[3], w4 = wr[4], w5 = wr[5];
      float s = xv[u];
      FMA4(a0, w0, s) FMA4(a1, w1, s) FMA4(a2, w2, s)
      FMA4(a3, w3, s) FMA4(a4, w4, s) FMA4(a5, w5, s)
    }
  }

  if (act) {
    float s0 = sc4(a0), s1 = sc4(a1), s2 = sc4(a2);
    float s3 = sc4(a3), s4 = sc4(a4), s5 = sc4(a5);
    float* mp = maxsc + (size_t)b * NANCH + (size_t)hwg * 6u;
    mp[0] = s0; mp[1] = s1; mp[2] = s2; mp[3] = s3; mp[4] = s4; mp[5] = s5;
    atomicAdd(&lh[sbin(__float_as_uint(s0))], 1u);
    atomicAdd(&lh[sbin(__float_as_uint(s1))], 1u);
    atomicAdd(&lh[sbin(__float_as_uint(s2))], 1u);
    atomicAdd(&lh[sbin(__float_as_uint(s3))], 1u);
    atomicAdd(&lh[sbin(__float_as_uint(s4))], 1u);
    atomicAdd(&lh[sbin(__float_as_uint(s5))], 1u);
  }
  __syncthreads();
  unsigned* gh = hist + (size_t)b * NBIN;
  for (int i = tid; i < NBIN; i += 256) {
    unsigned c = lh[i];
    if (c) atomicAdd(&gh[i], c);   // device-coherent; k3 reads after dispatch boundary
  }
}

// ---------------- K3: threshold scan (fused, redundant per block) + compact ----------------
// Every block recomputes the per-batch threshold from hist (deterministic:
// same inputs, same algorithm -> same T everywhere).  Saves the k2 dispatch.
__global__ __launch_bounds__(256) void k3_compact(
    const unsigned int* __restrict__ hist, const float* __restrict__ maxsc,
    unsigned int* __restrict__ cand_count, unsigned long long* __restrict__ cand) {
  int tid = threadIdx.x;
  unsigned p = blockIdx.x * 256u + tid;           // [0, B*NANCH)
  unsigned b = p / NANCH, n = p % NANCH;          // b block-uniform (NANCH%256==0)

  // --- fused k2: suffix-scan hist -> threshold bin T (block-local) ---
  __shared__ unsigned seg[256];
  __shared__ unsigned shT;
  const unsigned* h = hist + (size_t)b * NBIN;
  unsigned r[16];
  unsigned s = 0;
#pragma unroll
  for (int i = 0; i < 16; ++i) { r[i] = h[tid * 16 + i]; s += r[i]; }
  seg[tid] = s;
  __syncthreads();
  for (int d = 1; d < 256; d <<= 1) {   // inclusive suffix scan
    unsigned add = (tid + d < 256) ? seg[tid + d] : 0u;
    __syncthreads();
    seg[tid] += add;
    __syncthreads();
  }
  unsigned above = (tid < 255) ? seg[tid + 1] : 0u;
  if (above < TOPK && above + s >= TOPK) {   // exactly one thread
    unsigned c = above, T = 0;
    for (int i = 15; i >= 0; --i) {
      c += r[i];
      if (c >= TOPK) { T = tid * 16u + (unsigned)i; break; }
    }
    shT = T;
  }
  __syncthreads();
  unsigned T = shT;

  // --- compact (wave-aggregated atomics) ---
  unsigned bits = __float_as_uint(maxsc[p]);
  bool pred = sbin(bits) >= T;
  unsigned long long mask = __ballot(pred);
  if (mask) {
    int lane = tid & 63;
    int leader = (int)__ffsll(mask) - 1;
    unsigned base = 0;
    if (lane == leader)
      base = atomicAdd(&cand_count[b], (unsigned)__popcll(mask));
    base = __shfl(base, leader, 64);
    if (pred) {
      unsigned pos = base + (unsigned)__popcll(mask & ((1ull << lane) - 1ull));
      if (pos < CAP)
        cand[(size_t)b * CAP + pos] =
            ((unsigned long long)bits << 32) | (unsigned)(~n);
    }
  }
}

// ---------------- K4: bitonic sort candidates (1024 threads), emit topk ----------------
__global__ __launch_bounds__(1024) void k4_sort(
    const unsigned long long* __restrict__ cand,
    const unsigned int* __restrict__ cand_count, unsigned int* __restrict__ topk) {
  int b = blockIdx.x, tid = threadIdx.x;
  __shared__ unsigned long long sh[SMAX];
  unsigned cnt = cand_count[b];
  if (cnt > CAP) cnt = CAP;
  unsigned S = 128;
  while (S < cnt) S <<= 1;
  for (unsigned t = tid; t < S; t += 1024)
    sh[t] = (t < cnt) ? cand[(size_t)b * CAP + t] : 0ULL;
  __syncthreads();
  for (unsigned kk = 2; kk <= S; kk <<= 1) {
    for (unsigned jj = kk >> 1; jj > 0; jj >>= 1) {
      for (unsigned t = tid; t < S; t += 1024) {
        unsigned ixj = t ^ jj;
        if (ixj > t) {
          unsigned long long a = sh[t], c = sh[ixj];
          bool sw = ((t & kk) == 0) ? (a < c) : (a > c);  // descending
          if (sw) { sh[t] = c; sh[ixj] = a; }
        }
      }
      __syncthreads();
    }
  }
  if (tid < TOPK)
    topk[b * TOPK + tid] = ~(unsigned)(sh[tid] & 0xFFFFFFFFULL);
}

// ---------------- K5: final heads + decode for selected anchors ----------------
__global__ __launch_bounds__(256) void k5_out(
    const float* __restrict__ x, const float* __restrict__ cls_w,
    const float* __restrict__ cls_b, const float* __restrict__ reg_w,
    const float* __restrict__ reg_b, const float* __restrict__ anchors,
    const unsigned int* __restrict__ topk, float* __restrict__ out) {
  int bk = blockIdx.x;            // [0, B*TOPK)
  int b = bk / TOPK, k = bk % TOPK;
  unsigned n = topk[b * TOPK + k];
  int a = (int)(n % AA);
  unsigned hw = n / AA;
  int tid = threadIdx.x;          // 256 == CIN

  float xv = x[(size_t)b * CIN * HW + (size_t)tid * HW + hw];
  float part[11];
#pragma unroll
  for (int j = 0; j < 4; ++j) part[j] = xv * cls_w[(a * 4 + j) * CIN + tid];
#pragma unroll
  for (int j = 0; j < 7; ++j) part[4 + j] = xv * reg_w[(a * 7 + j) * CIN + tid];

#pragma unroll
  for (int j = 0; j < 11; ++j) {
    float v = part[j];
    for (int off = 32; off > 0; off >>= 1) v += __shfl_down(v, off, 64);
    part[j] = v;
  }
  __shared__ float red[4][11];
  int wave = tid >> 6, lane = tid & 63;
  if (lane == 0) {
#pragma unroll
    for (int j = 0; j < 11; ++j) red[wave][j] = part[j];
  }
  __syncthreads();
  if (tid == 0) {
    float tot[11];
#pragma unroll
    for (int j = 0; j < 11; ++j)
      tot[j] = red[0][j] + red[1][j] + red[2][j] + red[3][j];
    float l0 = tot[0] + cls_b[a * 4 + 0];
    float l1 = tot[1] + cls_b[a * 4 + 1];
    float l2 = tot[2] + cls_b[a * 4 + 2];
    float l3 = tot[3] + cls_b[a * 4 + 3];
    float m = fmaxf(fmaxf(l0, l1), fmaxf(l2, l3));
    float e0 = expf(l0 - m), e1 = expf(l1 - m);
    float e2 = expf(l2 - m), e3 = expf(l3 - m);
    float inv = 1.0f / (e0 + e1 + e2 + e3);
    float* os = out + ((size_t)b * TOPK + k) * 4;
    os[0] = e0 * inv; os[1] = e1 * inv; os[2] = e2 * inv; os[3] = e3 * inv;
    const float* an = anchors + (size_t)n * 7;
    float xa = an[0], ya = an[1], za = an[2];
    float dxa = an[3], dya = an[4], dza = an[5], ra = an[6];
    float xt = tot[4] + reg_b[a * 7 + 0];
    float yt = tot[5] + reg_b[a * 7 + 1];
    float zt = tot[6] + reg_b[a * 7 + 2];
    float dxt = tot[7] + reg_b[a * 7 + 3];
    float dyt = tot[8] + reg_b[a * 7 + 4];
    float dzt = tot[9] + reg_b[a * 7 + 5];
    float rt = tot[10] + reg_b[a * 7 + 6];
    float diag = sqrtf(dxa * dxa + dya * dya);
    float* ob = out + (size_t)BB * TOPK * 4 + ((size_t)b * TOPK + k) * 7;
    ob[0] = xt * diag + xa;
    ob[1] = yt * diag + ya;
    ob[2] = zt * dza + za;
    ob[3] = expf(dxt) * dxa;
    ob[4] = expf(dyt) * dya;
    ob[5] = expf(dzt) * dza;
    ob[6] = rt + ra;
  }
}

extern "C" void kernel_launch(void* const* d_in, const int* in_sizes, int n_in,
                              void* d_out, int out_size, void* d_ws, size_t ws_size,
                              hipStream_t stream) {
  const float* x       = (const float*)d_in[0];
  const float* cls_w   = (const float*)d_in[1];
  const float* cls_b   = (const float*)d_in[2];
  const float* reg_w   = (const float*)d_in[3];
  const float* reg_b   = (const float*)d_in[4];
  const float* anchors = (const float*)d_in[5];
  float* out = (float*)d_out;

  // workspace layout (~3.6 MB total; ws >= 4.7 MB available)
  char* ws = (char*)d_ws;
  unsigned int* hist       = (unsigned int*)(ws);                 // 64 KB
  unsigned int* cand_count = (unsigned int*)(ws + 65536);         // 64 B (zeroed with hist)
  unsigned int* topk       = (unsigned int*)(ws + 65664);         // 2 KB
  float* wt                = (float*)(ws + 67712);                // 24 KB transposed cls_w
  unsigned long long* cand = (unsigned long long*)(ws + 92288);   // 128 KB
  float* maxsc             = (float*)(ws + 223360);               // 3.4 MB

  // 5 dispatches; kernel boundaries provide cross-block coherence for free:
  k0_init<<<80, 256, 0, stream>>>(cls_w, wt, hist);   // hist..cand_count zero region
  k1_scores<<<BB * TILES, 256, 0, stream>>>(x, wt, cls_b, hist, maxsc);
  k3_compact<<<(BB * NANCH) / 256, 256, 0, stream>>>(hist, maxsc, cand_count, cand);
  k4_sort<<<BB, 1024, 0, stream>>>(cand, cand_count, topk);
  k5_out<<<BB * TOPK, 256, 0, stream>>>(x, cls_w, cls_b, reg_w, reg_b, anchors,
                                        topk, out);
}